// Round 9
// baseline (318.044 us; speedup 1.0000x reference)
//
#include <hip/hip_runtime.h>
#include <hip/hip_bf16.h>
#include <stdint.h>

#define BB 32
#define S_SRC 128
#define S_TGT 64
#define H 300
#define VV 32000
#define M_ROWS (BB * S_TGT)   // 2048
#define KP 320                // K padded to multiple of 32

#define MEGA_T 640
#define ENC_BLK 32
#define HDEC_BLK 128          // 16 rows each
#define WCVT_BLK 96

typedef __attribute__((ext_vector_type(8))) __bf16 bf16x8;
typedef __attribute__((ext_vector_type(4))) float f32x4;
typedef __attribute__((ext_vector_type(4))) unsigned short u16x4;
typedef __attribute__((ext_vector_type(2))) __fp16 f16x2;

#if defined(__has_builtin)
#if __has_builtin(__builtin_amdgcn_fdot2)
#define HAVE_FDOT2 1
#endif
#endif

__device__ inline unsigned short f2bf(float f) {
    union { float f; unsigned u; } v; v.f = f;
    unsigned r = (v.u + 0x7FFF + ((v.u >> 16) & 1)) >> 16;  // RNE
    return (unsigned short)r;
}

__device__ __forceinline__ float ftanh(float x) {
    float e = __builtin_amdgcn_exp2f(x * 2.8853900817779268f);
    return 1.0f - 2.0f * __builtin_amdgcn_rcpf(e + 1.0f);
}

__device__ __forceinline__ float fdot2(f16x2 a, f16x2 b, float c) {
#ifdef HAVE_FDOT2
    return __builtin_amdgcn_fdot2(a, b, c, false);
#else
    return c + (float)a.x * (float)b.x + (float)a.y * (float)b.y;
#endif
}

__device__ __forceinline__ void gl_lds16(const void* g, void* l) {
    __builtin_amdgcn_global_load_lds(
        (const __attribute__((address_space(1))) void*)g,
        (__attribute__((address_space(3))) void*)l, 16, 0, 0);
}

// ---------------- transpose enc_Wih, dec_Wih -> ws ----------------
__global__ void transpose2(const float* W0, const float* W1, float* dst) {
    const float* srcs[2] = {W0, W1};
    const float* src = srcs[blockIdx.z];
    float* d = dst + (size_t)blockIdx.z * (H * H);
    __shared__ float tile[32][33];
    int j0 = blockIdx.y * 32, k0 = blockIdx.x * 32;
    for (int r = threadIdx.y; r < 32; r += blockDim.y) {
        int j = j0 + r, k = k0 + threadIdx.x;
        tile[r][threadIdx.x] = (j < H && k < H) ? src[(size_t)j * H + k] : 0.f;
    }
    __syncthreads();
    for (int r = threadIdx.y; r < 32; r += blockDim.y) {
        int k = k0 + r, j = j0 + threadIdx.x;
        if (k < H && j < H) d[(size_t)k * H + j] = tile[threadIdx.x][r];
    }
}

// ---------------- P[m][j] = EN[x[m]] @ WihT + bih + bhh  (m = b*128+t) --------
#define RPB 16
__global__ __launch_bounds__(192) void pproj(const int* __restrict__ x,
                                             const float* __restrict__ EN,
                                             const float* __restrict__ WihT,
                                             const float* __restrict__ bih,
                                             const float* __restrict__ bhh,
                                             float* __restrict__ P) {
    __shared__ float xe[RPB][H];
    int m0 = blockIdx.x * RPB;
    int tid = threadIdx.x;
    for (int r = 0; r < RPB; ++r) {
        int idx = x[m0 + r];
        for (int c = tid; c < H; c += 192) xe[r][c] = EN[(size_t)idx * H + c];
    }
    __syncthreads();
    if (tid < 150) {
        int j = tid * 2;
        float a0[RPB], a1[RPB];
#pragma unroll
        for (int r = 0; r < RPB; ++r) { a0[r] = 0.f; a1[r] = 0.f; }
        const float* wp = WihT + j;
        for (int k = 0; k < H; k += 2) {
            float2 wa = *reinterpret_cast<const float2*>(wp + (size_t)k * H);
            float2 wb = *reinterpret_cast<const float2*>(wp + (size_t)(k + 1) * H);
#pragma unroll
            for (int r = 0; r < RPB; ++r) {
                float2 xv = *reinterpret_cast<const float2*>(&xe[r][k]);
                a0[r] += xv.x * wa.x + xv.y * wb.x;
                a1[r] += xv.x * wa.y + xv.y * wb.y;
            }
        }
        float b0 = bih[j] + bhh[j], b1 = bih[j + 1] + bhh[j + 1];
#pragma unroll
        for (int r = 0; r < RPB; ++r) {
            P[(size_t)(m0 + r) * H + j]     = a0[r] + b0;
            P[(size_t)(m0 + r) * H + j + 1] = a1[r] + b1;
        }
    }
}

// ---------------- MEGA kernel: 3 concurrent roles by blockIdx ----------------
__global__ __launch_bounds__(MEGA_T) void mega(
    const float* __restrict__ h0, const float* __restrict__ P,
    const float* __restrict__ Whh,
    const float* __restrict__ dWhh, const float* __restrict__ dbhh,
    float* __restrict__ s2,
    const int* __restrict__ yv, const float* __restrict__ ZH,
    const float* __restrict__ WihT_d, const float* __restrict__ bih_d,
    float* __restrict__ t1,
    const float* __restrict__ W, unsigned short* __restrict__ Wb) {
    __shared__ union {
        __fp16 hb[2][304];      // encoder h double-buffer (f16)
        float  ye[16][304];     // hdec embedding tile
    } L;
    int blk = blockIdx.x, tid = threadIdx.x;

    if (blk < ENC_BLK) {
        // ================= encoder =================
        int b = blk;
        bool act = tid < 600;
        int j = tid >> 1, half = tid & 1;   // row j, k-half
        f16x2 w[76];
        if (act) {
            const float* wr = Whh + (size_t)j * H + half * 150;
#pragma unroll
            for (int i = 0; i < 75; ++i) {
                float2 f = *reinterpret_cast<const float2*>(wr + 2 * i);
                w[i] = __builtin_amdgcn_cvt_pkrtz(f.x, f.y);
            }
            w[75] = __builtin_amdgcn_cvt_pkrtz(0.f, 0.f);
        }
        if (act && half == 0) {
            int pos = j < 150 ? j : j + 2;
            L.hb[0][pos] = (__fp16)h0[(size_t)b * H + j];
        }
        if (tid >= 600 && tid < 608) {
            int pi = tid - 600, bufi = pi >> 2, q = pi & 3;
            int idx = (q < 2) ? (150 + q) : (302 + (q - 2));
            L.hb[bufi][idx] = (__fp16)0.f;
        }
        __syncthreads();

        const float* Pb = P + (size_t)b * S_SRC * H;
        int cur = 0;
        for (int t = 0; t < S_SRC; ++t) {
            float pv = 0.f;
            if (act && half == 0) pv = Pb[(size_t)t * H + j];   // hides under dots
            if (act) {
                float a0 = 0.f, a1 = 0.f, a2 = 0.f, a3 = 0.f;
                const uint2* hp =
                    reinterpret_cast<const uint2*>(&L.hb[cur][half * 152]);
#pragma unroll
                for (int i = 0; i < 38; i += 2) {
                    uint2 qa = hp[i];
                    uint2 qb = hp[i + 1];
                    a0 = fdot2(w[2 * i],     __builtin_bit_cast(f16x2, qa.x), a0);
                    a1 = fdot2(w[2 * i + 1], __builtin_bit_cast(f16x2, qa.y), a1);
                    a2 = fdot2(w[2 * i + 2], __builtin_bit_cast(f16x2, qb.x), a2);
                    a3 = fdot2(w[2 * i + 3], __builtin_bit_cast(f16x2, qb.y), a3);
                }
                float a = (a0 + a1) + (a2 + a3);
                float tot = a + __shfl_xor(a, 1, 64);   // pair (2j,2j+1) same wave
                if (half == 0) {
                    float hv = ftanh(tot + pv);
                    int pos = j < 150 ? j : j + 2;
                    L.hb[cur ^ 1][pos] = (__fp16)hv;
                }
            }
            __syncthreads();
            cur ^= 1;
        }
        // ===== fused s2 tail: s2[b] = h @ dWhh^T + dbhh =====
        if (act) {
            const float* wr = dWhh + (size_t)j * H + half * 150;
            const uint2* hp = reinterpret_cast<const uint2*>(&L.hb[cur][half * 152]);
            float a0 = 0.f, a1 = 0.f;
#pragma unroll
            for (int i = 0; i < 37; ++i) {
                uint2 q = hp[i];
                f16x2 hA = __builtin_bit_cast(f16x2, q.x);
                f16x2 hB = __builtin_bit_cast(f16x2, q.y);
                float4 wf = *reinterpret_cast<const float4*>(wr + 4 * i);
                a0 += wf.x * (float)hA.x + wf.y * (float)hA.y;
                a1 += wf.z * (float)hB.x + wf.w * (float)hB.y;
            }
            {
                f16x2 hA = __builtin_bit_cast(f16x2,
                    reinterpret_cast<const uint*>(&L.hb[cur][half * 152])[74]);
                float2 wf = *reinterpret_cast<const float2*>(wr + 148);
                a0 += wf.x * (float)hA.x + wf.y * (float)hA.y;
            }
            float a = a0 + a1;
            float tot = a + __shfl_xor(a, 1, 64);
            if (half == 0) s2[(size_t)b * H + j] = tot + dbhh[j];
        }
    } else if (blk < ENC_BLK + HDEC_BLK) {
        // ================= hdec partial GEMM =================
        int bi = blk - ENC_BLK;
        int m0 = bi * 16;
        for (int i = tid; i < 16 * 304; i += MEGA_T) {
            int r = i / 304, cc = i - r * 304;
            L.ye[r][cc] = (cc < H) ? ZH[(size_t)yv[m0 + r] * H + cc] : 0.f;
        }
        __syncthreads();
        if (tid < 600) {
            int rg = tid / 150, jp = tid - rg * 150, j0 = 2 * jp;
            float a[4][2] = {};
            const float* wp = WihT_d + j0;
            for (int k = 0; k < H; k += 2) {
                float2 wa = *reinterpret_cast<const float2*>(wp + (size_t)k * H);
                float2 wb = *reinterpret_cast<const float2*>(wp + (size_t)(k + 1) * H);
#pragma unroll
                for (int r = 0; r < 4; ++r) {
                    float2 x = *reinterpret_cast<const float2*>(&L.ye[rg * 4 + r][k]);
                    a[r][0] += x.x * wa.x + x.y * wb.x;
                    a[r][1] += x.x * wa.y + x.y * wb.y;
                }
            }
            float b0 = bih_d[j0], b1 = bih_d[j0 + 1];
#pragma unroll
            for (int r = 0; r < 4; ++r) {
                *reinterpret_cast<float2*>(&t1[(size_t)(m0 + rg * 4 + r) * 304 + j0]) =
                    make_float2(a[r][0] + b0, a[r][1] + b1);
            }
        }
    } else if (Wb != nullptr) {
        // ================= wcvt =================
        for (int id = (blk - (ENC_BLK + HDEC_BLK)) * MEGA_T + tid; id < VV * 80;
             id += WCVT_BLK * MEGA_T) {
            int row = id / 80, cq = id - row * 80;
            int k = cq * 4;
            u16x4 o;
            if (k < H) {
                float4 f = *reinterpret_cast<const float4*>(W + (size_t)row * H + k);
                o[0] = f2bf(f.x); o[1] = f2bf(f.y); o[2] = f2bf(f.z); o[3] = f2bf(f.w);
            } else {
                o[0] = 0; o[1] = 0; o[2] = 0; o[3] = 0;
            }
            *reinterpret_cast<u16x4*>(Wb + (size_t)row * KP + k) = o;
        }
    }
}

// ---------------- hdec[m][j] = bf16(tanh(t1[m][j] + s2[b][j])), pad to 320 ---
__global__ __launch_bounds__(256) void hdec_fin(const float* __restrict__ t1,
                                                const float* __restrict__ s2,
                                                unsigned short* __restrict__ hdec) {
    int blk = blockIdx.x, tid = threadIdx.x;   // 256 blocks x 8 rows
    for (int i = tid; i < 8 * KP; i += 256) {
        int r = i / KP, j = i - r * KP;
        int m = blk * 8 + r, b = m >> 6;
        unsigned short v = 0;
        if (j < H)
            v = f2bf(ftanh(t1[(size_t)m * 304 + j] + s2[(size_t)b * H + j]));
        hdec[(size_t)m * KP + j] = v;
    }
}

// ---------------- out = hdec[2048,320] @ Wb[32000,320]^T + b_out -------------
// gemm2 structure (proven best) at BK=32: 32 KB LDS -> 4 blocks/CU so epilogue
// writes / staging / barrier drains overlap across blocks. 2-way-max LDS
// aliasing via (row>>1)&3 XOR swizzle (both-sides, gl_lds dest linear).
__global__ __launch_bounds__(256, 4) void gemm5(const unsigned short* __restrict__ A,
                                                const unsigned short* __restrict__ Wb,
                                                const float* __restrict__ bout,
                                                float* __restrict__ out) {
    __shared__ unsigned short Al[2][128 * 32];
    __shared__ unsigned short Bl[2][128 * 32];
    int tid = threadIdx.x;
    int lane = tid & 63, wv = tid >> 6;
    int wm = wv >> 1, wn = wv & 1;            // 2x2 waves, 64x64 each

    int orig = blockIdx.x;                    // 4000 blocks
    int wg = (orig & 7) * 500 + (orig >> 3);  // bijective XCD swizzle (4000%8==0)
    int mi = wg & 15, ni = wg >> 4;           // m-fastest
    int m0 = mi * 128, n0 = ni * 128;

    int rowq = tid >> 2;                      // 0..63
    int scn = (tid & 3) ^ ((rowq >> 1) & 3);  // pre-swizzled source chunk

    const unsigned short* Ab = A + (size_t)m0 * KP;
    const unsigned short* Bb = Wb + (size_t)n0 * KP;

    f32x4 acc[4][4];
    f32x4 zero = {0.f, 0.f, 0.f, 0.f};
#pragma unroll
    for (int i = 0; i < 4; ++i)
#pragma unroll
        for (int j = 0; j < 4; ++j) acc[i][j] = zero;

#define STAGE5(T)                                                              \
    {                                                                          \
        int kk_ = (T) * 32;                                                    \
        int bf_ = (T) & 1;                                                     \
        _Pragma("unroll")                                                      \
        for (int s_ = 0; s_ < 2; ++s_) {                                       \
            int row_ = s_ * 64 + rowq;                                         \
            gl_lds16(Ab + (size_t)row_ * KP + kk_ + scn * 8,                   \
                     &Al[bf_][(s_ * 256 + tid) * 8]);                          \
        }                                                                      \
        _Pragma("unroll")                                                      \
        for (int s_ = 0; s_ < 2; ++s_) {                                       \
            int row_ = s_ * 64 + rowq;                                         \
            gl_lds16(Bb + (size_t)row_ * KP + kk_ + scn * 8,                   \
                     &Bl[bf_][(s_ * 256 + tid) * 8]);                          \
        }                                                                      \
    }

    STAGE5(0)

#pragma unroll
    for (int t = 0; t < 10; ++t) {
        __syncthreads();          // drains vmcnt: stage(t) visible; prev reads done
        if (t < 9) STAGE5(t + 1)  // into buf t+1 (last read in iter t-1): safe
        int bf = t & 1;
        int ch = (lane >> 4) ^ (((lane & 15) >> 1) & 3);   // read-side XOR
        bf16x8 af[4], bb[4];
#pragma unroll
        for (int i = 0; i < 4; ++i) {
            int rowA = wm * 64 + i * 16 + (lane & 15);
            af[i] = *reinterpret_cast<const bf16x8*>(&Al[bf][rowA * 32 + ch * 8]);
            int rowB = wn * 64 + i * 16 + (lane & 15);
            bb[i] = *reinterpret_cast<const bf16x8*>(&Bl[bf][rowB * 32 + ch * 8]);
        }
#pragma unroll
        for (int i = 0; i < 4; ++i)
#pragma unroll
            for (int j = 0; j < 4; ++j)
                acc[i][j] = __builtin_amdgcn_mfma_f32_16x16x32_bf16(
                    af[i], bb[j], acc[i][j], 0, 0, 0);
    }
#undef STAGE5

    // epilogue: D row=(lane>>4)*4+r, col=lane&15
#pragma unroll
    for (int j = 0; j < 4; ++j) {
        int col = n0 + wn * 64 + j * 16 + (lane & 15);
        float bo = bout[col];
#pragma unroll
        for (int i = 0; i < 4; ++i) {
            int rb = m0 + wm * 64 + i * 16 + (lane >> 4) * 4;
            f32x4 v = acc[i][j];
#pragma unroll
            for (int r = 0; r < 4; ++r)
                out[(size_t)(rb + r) * VV + col] = v[r] + bo;
        }
    }
}

// ---------------- fallback GEMM (reads W f32) for small ws -------------------
#define LDSW 40
__global__ __launch_bounds__(256) void gemm_out(const unsigned short* __restrict__ A,
                                                const float* __restrict__ W,
                                                const float* __restrict__ bout,
                                                float* __restrict__ out) {
    __shared__ __align__(16) unsigned short Alds[128 * LDSW];
    __shared__ __align__(16) unsigned short Bl[128 * LDSW];
    int tid = threadIdx.x;
    int lane = tid & 63, wv = tid >> 6;
    int wm = wv >> 1, wn = wv & 1;
    int m0 = blockIdx.y * 128, n0 = blockIdx.x * 128;

    f32x4 acc[4][4];
    f32x4 zero = {0.f, 0.f, 0.f, 0.f};
#pragma unroll
    for (int i = 0; i < 4; ++i)
#pragma unroll
        for (int jj = 0; jj < 4; ++jj) acc[i][jj] = zero;

    for (int k0 = 0; k0 < KP; k0 += 32) {
#pragma unroll
        for (int s = 0; s < 2; ++s) {
            int slot = tid + s * 256;
            int row = slot >> 2, c16 = slot & 3;
            uint4 v = *reinterpret_cast<const uint4*>(
                &A[(size_t)(m0 + row) * KP + k0 + c16 * 8]);
            *reinterpret_cast<uint4*>(&Alds[row * LDSW + c16 * 8]) = v;
        }
#pragma unroll
        for (int s = 0; s < 2; ++s) {
            int slot = tid + s * 256;
            int row = slot >> 2, c8 = slot & 3;
            int k = k0 + c8 * 8;
            __align__(16) unsigned short tmp[8];
            if (k + 7 < H) {
                const float* src = &W[(size_t)(n0 + row) * H + k];
                float4 f0 = *reinterpret_cast<const float4*>(src);
                float4 f1 = *reinterpret_cast<const float4*>(src + 4);
                tmp[0] = f2bf(f0.x); tmp[1] = f2bf(f0.y);
                tmp[2] = f2bf(f0.z); tmp[3] = f2bf(f0.w);
                tmp[4] = f2bf(f1.x); tmp[5] = f2bf(f1.y);
                tmp[6] = f2bf(f1.z); tmp[7] = f2bf(f1.w);
            } else {
#pragma unroll
                for (int jv = 0; jv < 8; ++jv) {
                    int kk = k + jv;
                    tmp[jv] = (kk < H) ? f2bf(W[(size_t)(n0 + row) * H + kk])
                                       : (unsigned short)0;
                }
            }
            *reinterpret_cast<uint4*>(&Bl[row * LDSW + c8 * 8]) =
                *reinterpret_cast<const uint4*>(tmp);
        }
        __syncthreads();
        bf16x8 af[4], bfm[4];
#pragma unroll
        for (int i = 0; i < 4; ++i) {
            int row = wm * 64 + i * 16 + (lane & 15);
            af[i] = *reinterpret_cast<const bf16x8*>(&Alds[row * LDSW + (lane >> 4) * 8]);
        }
#pragma unroll
        for (int i = 0; i < 4; ++i) {
            int row = wn * 64 + i * 16 + (lane & 15);
            bfm[i] = *reinterpret_cast<const bf16x8*>(&Bl[row * LDSW + (lane >> 4) * 8]);
        }
#pragma unroll
        for (int i = 0; i < 4; ++i)
#pragma unroll
            for (int jj = 0; jj < 4; ++jj)
                acc[i][jj] = __builtin_amdgcn_mfma_f32_16x16x32_bf16(
                    af[i], bfm[jj], acc[i][jj], 0, 0, 0);
        __syncthreads();
    }
#pragma unroll
    for (int jj = 0; jj < 4; ++jj) {
        int col = n0 + wn * 64 + jj * 16 + (lane & 15);
        float bo = bout[col];
#pragma unroll
        for (int i = 0; i < 4; ++i) {
            int rb = m0 + wm * 64 + i * 16 + (lane >> 4) * 4;
            f32x4 v = acc[i][jj];
#pragma unroll
            for (int r = 0; r < 4; ++r)
                out[(size_t)(rb + r) * VV + col] = v[r] + bo;
        }
    }
}

// ---------------- host ----------------
extern "C" void kernel_launch(void* const* d_in, const int* in_sizes, int n_in,
                              void* d_out, int out_size, void* d_ws, size_t ws_size,
                              hipStream_t stream) {
    const int*   x       = (const int*)d_in[0];
    const int*   y       = (const int*)d_in[1];
    const float* h0      = (const float*)d_in[2];
    const float* EN      = (const float*)d_in[3];
    const float* ZH      = (const float*)d_in[4];
    const float* enc_Wih = (const float*)d_in[5];
    const float* enc_Whh = (const float*)d_in[6];
    const float* enc_bih = (const float*)d_in[7];
    const float* enc_bhh = (const float*)d_in[8];
    const float* dec_Wih = (const float*)d_in[9];
    const float* dec_Whh = (const float*)d_in[10];
    const float* dec_bih = (const float*)d_in[11];
    const float* dec_bhh = (const float*)d_in[12];
    const float* W_out   = (const float*)d_in[13];
    const float* b_out   = (const float*)d_in[14];
    float* out = (float*)d_out;
    char* base = (char*)d_ws;

    const size_t needA = 22549120, needB = 2069120;
    bool bigws = (ws_size >= needA);
    if (!bigws && ws_size < needB) return;

    float* WT = (float*)base;
    float *s2_;
    unsigned short *hdec, *Wb = nullptr;
    if (bigws) {
        Wb   = (unsigned short*)(base + 720000);
        s2_  = (float*)(base + 21200000);
        hdec = (unsigned short*)(base + 21238400);
    } else {
        s2_  = (float*)(base + 720000);
        hdec = (unsigned short*)(base + 758400);
    }
    float* P  = out;                 // [4096x300] f32 (d_out scratch, dead before GEMM)
    float* t1 = out + 2000000;       // [2048x304] f32 (disjoint)

    transpose2<<<dim3(10, 10, 2), dim3(32, 8), 0, stream>>>(enc_Wih, dec_Wih, WT);
    pproj<<<(BB * S_SRC) / RPB, 192, 0, stream>>>(x, EN, WT, enc_bih, enc_bhh, P);
    int mega_grid = bigws ? (ENC_BLK + HDEC_BLK + WCVT_BLK) : (ENC_BLK + HDEC_BLK);
    mega<<<mega_grid, MEGA_T, 0, stream>>>(h0, P, enc_Whh, dec_Whh, dec_bhh, s2_,
                                           y, ZH, WT + 90000, dec_bih, t1,
                                           W_out, Wb);
    hdec_fin<<<M_ROWS / 8, 256, 0, stream>>>(t1, s2_, hdec);
    if (bigws) {
        gemm5<<<4000, 256, 0, stream>>>(hdec, Wb, b_out, out);
    } else {
        gemm_out<<<dim3(VV / 128, M_ROWS / 128), 256, 0, stream>>>(hdec, W_out, b_out, out);
    }
}

// Round 10
// 260.908 us; speedup vs baseline: 1.2190x; 1.2190x over previous
//
#include <hip/hip_runtime.h>
#include <hip/hip_bf16.h>
#include <stdint.h>

#define BB 32
#define S_SRC 128
#define S_TGT 64
#define H 300
#define VV 32000
#define M_ROWS (BB * S_TGT)   // 2048
#define KP 320                // K padded to multiple of 64

#define MEGA_T 640
#define ENC_BLK 32
#define HDEC_BLK 128          // 16 rows each
#define WCVT_BLK 96

typedef __attribute__((ext_vector_type(8))) __bf16 bf16x8;
typedef __attribute__((ext_vector_type(4))) float f32x4;
typedef __attribute__((ext_vector_type(4))) unsigned short u16x4;
typedef __attribute__((ext_vector_type(2))) __fp16 f16x2;

#if defined(__has_builtin)
#if __has_builtin(__builtin_amdgcn_fdot2)
#define HAVE_FDOT2 1
#endif
#endif

__device__ inline unsigned short f2bf(float f) {
    union { float f; unsigned u; } v; v.f = f;
    unsigned r = (v.u + 0x7FFF + ((v.u >> 16) & 1)) >> 16;  // RNE
    return (unsigned short)r;
}

__device__ __forceinline__ float ftanh(float x) {
    float e = __builtin_amdgcn_exp2f(x * 2.8853900817779268f);
    return 1.0f - 2.0f * __builtin_amdgcn_rcpf(e + 1.0f);
}

__device__ __forceinline__ float fdot2(f16x2 a, f16x2 b, float c) {
#ifdef HAVE_FDOT2
    return __builtin_amdgcn_fdot2(a, b, c, false);
#else
    return c + (float)a.x * (float)b.x + (float)a.y * (float)b.y;
#endif
}

__device__ __forceinline__ void gl_lds16(const void* g, void* l) {
    __builtin_amdgcn_global_load_lds(
        (const __attribute__((address_space(1))) void*)g,
        (__attribute__((address_space(3))) void*)l, 16, 0, 0);
}

// ---------------- transpose enc_Wih, dec_Wih -> ws ----------------
__global__ void transpose2(const float* W0, const float* W1, float* dst) {
    const float* srcs[2] = {W0, W1};
    const float* src = srcs[blockIdx.z];
    float* d = dst + (size_t)blockIdx.z * (H * H);
    __shared__ float tile[32][33];
    int j0 = blockIdx.y * 32, k0 = blockIdx.x * 32;
    for (int r = threadIdx.y; r < 32; r += blockDim.y) {
        int j = j0 + r, k = k0 + threadIdx.x;
        tile[r][threadIdx.x] = (j < H && k < H) ? src[(size_t)j * H + k] : 0.f;
    }
    __syncthreads();
    for (int r = threadIdx.y; r < 32; r += blockDim.y) {
        int k = k0 + r, j = j0 + threadIdx.x;
        if (k < H && j < H) d[(size_t)k * H + j] = tile[threadIdx.x][r];
    }
}

// ---------------- P[m][j] = EN[x[m]] @ WihT + bih + bhh  (m = b*128+t) --------
#define RPB 8
__global__ __launch_bounds__(192) void pproj(const int* __restrict__ x,
                                             const float* __restrict__ EN,
                                             const float* __restrict__ WihT,
                                             const float* __restrict__ bih,
                                             const float* __restrict__ bhh,
                                             float* __restrict__ P) {
    __shared__ float xe[RPB][H];
    int m0 = blockIdx.x * RPB;
    int tid = threadIdx.x;
    for (int r = 0; r < RPB; ++r) {
        int idx = x[m0 + r];
        for (int c = tid; c < H; c += 192) xe[r][c] = EN[(size_t)idx * H + c];
    }
    __syncthreads();
    if (tid < 150) {
        int j = tid * 2;
        float a0[RPB], a1[RPB];
#pragma unroll
        for (int r = 0; r < RPB; ++r) { a0[r] = 0.f; a1[r] = 0.f; }
        const float* wp = WihT + j;
        for (int k = 0; k < H; ++k) {
            float2 w = *reinterpret_cast<const float2*>(wp + (size_t)k * H);
#pragma unroll
            for (int r = 0; r < RPB; ++r) {
                float xv = xe[r][k];
                a0[r] += xv * w.x; a1[r] += xv * w.y;
            }
        }
        float b0 = bih[j] + bhh[j], b1 = bih[j + 1] + bhh[j + 1];
#pragma unroll
        for (int r = 0; r < RPB; ++r) {
            P[(size_t)(m0 + r) * H + j]     = a0[r] + b0;
            P[(size_t)(m0 + r) * H + j + 1] = a1[r] + b1;
        }
    }
}

// ---------------- MEGA kernel: 3 concurrent roles by blockIdx ----------------
__global__ __launch_bounds__(MEGA_T) void mega(
    const float* __restrict__ h0, const float* __restrict__ P,
    const float* __restrict__ Whh,
    const float* __restrict__ dWhh, const float* __restrict__ dbhh,
    float* __restrict__ s2,
    const int* __restrict__ yv, const float* __restrict__ ZH,
    const float* __restrict__ WihT_d, const float* __restrict__ bih_d,
    float* __restrict__ t1,
    const float* __restrict__ W, unsigned short* __restrict__ Wb) {
    __shared__ union {
        __fp16 hb[2][304];      // encoder h double-buffer (f16)
        float  ye[16][304];     // hdec embedding tile
    } L;
    int blk = blockIdx.x, tid = threadIdx.x;

    if (blk < ENC_BLK) {
        // ================= encoder =================
        int b = blk;
        bool act = tid < 600;
        int j = tid >> 1, half = tid & 1;   // row j, k-half
        f16x2 w[76];
        if (act) {
            const float* wr = Whh + (size_t)j * H + half * 150;
#pragma unroll
            for (int i = 0; i < 75; ++i) {
                float2 f = *reinterpret_cast<const float2*>(wr + 2 * i);
                w[i] = __builtin_amdgcn_cvt_pkrtz(f.x, f.y);
            }
            w[75] = __builtin_amdgcn_cvt_pkrtz(0.f, 0.f);
        }
        if (act && half == 0) {
            int pos = j < 150 ? j : j + 2;
            L.hb[0][pos] = (__fp16)h0[(size_t)b * H + j];
        }
        if (tid >= 600 && tid < 608) {
            int pi = tid - 600, bufi = pi >> 2, q = pi & 3;
            int idx = (q < 2) ? (150 + q) : (302 + (q - 2));
            L.hb[bufi][idx] = (__fp16)0.f;
        }
        __syncthreads();

        const float* Pb = P + (size_t)b * S_SRC * H;
        int cur = 0;
        for (int t = 0; t < S_SRC; ++t) {
            float pv = 0.f;
            if (act && half == 0) pv = Pb[(size_t)t * H + j];   // hides under dots
            if (act) {
                float a0 = 0.f, a1 = 0.f, a2 = 0.f, a3 = 0.f;
                const uint2* hp =
                    reinterpret_cast<const uint2*>(&L.hb[cur][half * 152]);
#pragma unroll
                for (int i = 0; i < 38; i += 2) {
                    uint2 qa = hp[i];
                    uint2 qb = hp[i + 1];
                    a0 = fdot2(w[2 * i],     __builtin_bit_cast(f16x2, qa.x), a0);
                    a1 = fdot2(w[2 * i + 1], __builtin_bit_cast(f16x2, qa.y), a1);
                    a2 = fdot2(w[2 * i + 2], __builtin_bit_cast(f16x2, qb.x), a2);
                    a3 = fdot2(w[2 * i + 3], __builtin_bit_cast(f16x2, qb.y), a3);
                }
                float a = (a0 + a1) + (a2 + a3);
                float tot = a + __shfl_xor(a, 1, 64);   // pair (2j,2j+1) same wave
                if (half == 0) {
                    float hv = ftanh(tot + pv);
                    int pos = j < 150 ? j : j + 2;
                    L.hb[cur ^ 1][pos] = (__fp16)hv;
                }
            }
            __syncthreads();
            cur ^= 1;
        }
        // ===== fused s2 tail: s2[b] = h @ dWhh^T + dbhh =====
        if (act) {
            const float* wr = dWhh + (size_t)j * H + half * 150;
            const uint2* hp = reinterpret_cast<const uint2*>(&L.hb[cur][half * 152]);
            float a0 = 0.f, a1 = 0.f;
#pragma unroll
            for (int i = 0; i < 37; ++i) {
                uint2 q = hp[i];
                f16x2 hA = __builtin_bit_cast(f16x2, q.x);
                f16x2 hB = __builtin_bit_cast(f16x2, q.y);
                float4 wf = *reinterpret_cast<const float4*>(wr + 4 * i);
                a0 += wf.x * (float)hA.x + wf.y * (float)hA.y;
                a1 += wf.z * (float)hB.x + wf.w * (float)hB.y;
            }
            {
                f16x2 hA = __builtin_bit_cast(f16x2,
                    reinterpret_cast<const uint*>(&L.hb[cur][half * 152])[74]);
                float2 wf = *reinterpret_cast<const float2*>(wr + 148);
                a0 += wf.x * (float)hA.x + wf.y * (float)hA.y;
            }
            float a = a0 + a1;
            float tot = a + __shfl_xor(a, 1, 64);
            if (half == 0) s2[(size_t)b * H + j] = tot + dbhh[j];
        }
    } else if (blk < ENC_BLK + HDEC_BLK) {
        // ================= hdec partial GEMM =================
        int bi = blk - ENC_BLK;
        int m0 = bi * 16;
        for (int i = tid; i < 16 * 304; i += MEGA_T) {
            int r = i / 304, cc = i - r * 304;
            L.ye[r][cc] = (cc < H) ? ZH[(size_t)yv[m0 + r] * H + cc] : 0.f;
        }
        __syncthreads();
        if (tid < 600) {
            int rg = tid / 150, jp = tid - rg * 150, j0 = 2 * jp;
            float a[4][2] = {};
            const float* wp = WihT_d + j0;
            for (int k = 0; k < H; k += 2) {
                float2 wa = *reinterpret_cast<const float2*>(wp + (size_t)k * H);
                float2 wb = *reinterpret_cast<const float2*>(wp + (size_t)(k + 1) * H);
#pragma unroll
                for (int r = 0; r < 4; ++r) {
                    float2 x = *reinterpret_cast<const float2*>(&L.ye[rg * 4 + r][k]);
                    a[r][0] += x.x * wa.x + x.y * wb.x;
                    a[r][1] += x.x * wa.y + x.y * wb.y;
                }
            }
            float b0 = bih_d[j0], b1 = bih_d[j0 + 1];
#pragma unroll
            for (int r = 0; r < 4; ++r) {
                *reinterpret_cast<float2*>(&t1[(size_t)(m0 + rg * 4 + r) * 304 + j0]) =
                    make_float2(a[r][0] + b0, a[r][1] + b1);
            }
        }
    } else if (Wb != nullptr) {
        // ================= wcvt =================
        for (int id = (blk - (ENC_BLK + HDEC_BLK)) * MEGA_T + tid; id < VV * 80;
             id += WCVT_BLK * MEGA_T) {
            int row = id / 80, cq = id - row * 80;
            int k = cq * 4;
            u16x4 o;
            if (k < H) {
                float4 f = *reinterpret_cast<const float4*>(W + (size_t)row * H + k);
                o[0] = f2bf(f.x); o[1] = f2bf(f.y); o[2] = f2bf(f.z); o[3] = f2bf(f.w);
            } else {
                o[0] = 0; o[1] = 0; o[2] = 0; o[3] = 0;
            }
            *reinterpret_cast<u16x4*>(Wb + (size_t)row * KP + k) = o;
        }
    }
}

// ---------------- hdec[m][j] = bf16(tanh(t1[m][j] + s2[b][j])), pad to 320 ---
__global__ __launch_bounds__(256) void hdec_fin(const float* __restrict__ t1,
                                                const float* __restrict__ s2,
                                                unsigned short* __restrict__ hdec) {
    int blk = blockIdx.x, tid = threadIdx.x;   // 256 blocks x 8 rows
    for (int i = tid; i < 8 * KP; i += 256) {
        int r = i / KP, j = i - r * KP;
        int m = blk * 8 + r, b = m >> 6;
        unsigned short v = 0;
        if (j < H)
            v = f2bf(ftanh(t1[(size_t)m * 304 + j] + s2[(size_t)b * H + j]));
        hdec[(size_t)m * KP + j] = v;
    }
}

// ---------------- out = hdec[2048,320] @ Wb[32000,320]^T + b_out -------------
// PROVEN BEST (rounds 3-6): 128x128 tile, BK=64, dbuf LDS, gl_lds w16,
// prefetch issued right after the barrier (32 MFMAs of latency cover),
// both-sides XOR chunk swizzle, XCD-bijective + m-fastest block swizzle.
__global__ __launch_bounds__(256) void gemm2(const unsigned short* __restrict__ A,
                                             const unsigned short* __restrict__ Wb,
                                             const float* __restrict__ bout,
                                             float* __restrict__ out) {
    __shared__ unsigned short Al[2][128 * 64];
    __shared__ unsigned short Blds[2][128 * 64];
    int tid = threadIdx.x;
    int lane = tid & 63, wv = tid >> 6;
    int wm = wv >> 1, wn = wv & 1;           // 2x2 waves, 64x64 each

    int orig = blockIdx.x;                    // 4000 blocks
    int wg = (orig & 7) * 500 + (orig >> 3);  // bijective XCD swizzle (4000%8==0)
    int mi = wg & 15, ni = wg >> 4;           // m-fastest
    int m0 = mi * 128, n0 = ni * 128;

    int rowb = tid >> 3;
    int sc2 = (tid & 7) ^ (rowb & 7);         // pre-swizzled source chunk

    f32x4 acc[4][4];
    f32x4 zero = {0.f, 0.f, 0.f, 0.f};
#pragma unroll
    for (int i = 0; i < 4; ++i)
#pragma unroll
        for (int j = 0; j < 4; ++j) acc[i][j] = zero;

    // prologue stage k-tile 0 into buf 0
#pragma unroll
    for (int i = 0; i < 4; ++i) {
        int row = i * 32 + rowb;
        gl_lds16(A + (size_t)(m0 + row) * KP + sc2 * 8, &Al[0][(i * 256 + tid) * 8]);
    }
#pragma unroll
    for (int i = 0; i < 4; ++i) {
        int row = i * 32 + rowb;
        gl_lds16(Wb + (size_t)(n0 + row) * KP + sc2 * 8, &Blds[0][(i * 256 + tid) * 8]);
    }

    for (int t = 0; t < 5; ++t) {
        __syncthreads();   // drains vmcnt: stage(t) visible; prev reads done
        int buf = t & 1;
        if (t < 4) {       // prefetch first: max latency cover before next barrier
            int k0 = (t + 1) * 64, nb = buf ^ 1;
#pragma unroll
            for (int i = 0; i < 4; ++i) {
                int row = i * 32 + rowb;
                gl_lds16(A + (size_t)(m0 + row) * KP + k0 + sc2 * 8,
                         &Al[nb][(i * 256 + tid) * 8]);
            }
#pragma unroll
            for (int i = 0; i < 4; ++i) {
                int row = i * 32 + rowb;
                gl_lds16(Wb + (size_t)(n0 + row) * KP + k0 + sc2 * 8,
                         &Blds[nb][(i * 256 + tid) * 8]);
            }
        }
        bf16x8 af[2][4], bb[2][4];
#pragma unroll
        for (int ks = 0; ks < 2; ++ks)
#pragma unroll
            for (int i = 0; i < 4; ++i) {
                int ch = (ks * 4 + (lane >> 4)) ^ (lane & 7);  // read-side XOR
                int rowA = wm * 64 + i * 16 + (lane & 15);
                af[ks][i] = *reinterpret_cast<const bf16x8*>(&Al[buf][rowA * 64 + ch * 8]);
                int rowB = wn * 64 + i * 16 + (lane & 15);
                bb[ks][i] = *reinterpret_cast<const bf16x8*>(&Blds[buf][rowB * 64 + ch * 8]);
            }
#pragma unroll
        for (int ks = 0; ks < 2; ++ks)
#pragma unroll
            for (int i = 0; i < 4; ++i)
#pragma unroll
                for (int j = 0; j < 4; ++j)
                    acc[i][j] = __builtin_amdgcn_mfma_f32_16x16x32_bf16(
                        af[ks][i], bb[ks][j], acc[i][j], 0, 0, 0);
    }

    // epilogue: D row=(lane>>4)*4+r, col=lane&15
#pragma unroll
    for (int j = 0; j < 4; ++j) {
        int col = n0 + wn * 64 + j * 16 + (lane & 15);
        float bo = bout[col];
#pragma unroll
        for (int i = 0; i < 4; ++i) {
            int rb = m0 + wm * 64 + i * 16 + (lane >> 4) * 4;
            f32x4 v = acc[i][j];
#pragma unroll
            for (int r = 0; r < 4; ++r)
                out[(size_t)(rb + r) * VV + col] = v[r] + bo;
        }
    }
}

// ---------------- fallback GEMM (reads W f32) for small ws -------------------
#define LDSW 40
__global__ __launch_bounds__(256) void gemm_out(const unsigned short* __restrict__ A,
                                                const float* __restrict__ W,
                                                const float* __restrict__ bout,
                                                float* __restrict__ out) {
    __shared__ __align__(16) unsigned short Alds[128 * LDSW];
    __shared__ __align__(16) unsigned short Bl[128 * LDSW];
    int tid = threadIdx.x;
    int lane = tid & 63, wv = tid >> 6;
    int wm = wv >> 1, wn = wv & 1;
    int m0 = blockIdx.y * 128, n0 = blockIdx.x * 128;

    f32x4 acc[4][4];
    f32x4 zero = {0.f, 0.f, 0.f, 0.f};
#pragma unroll
    for (int i = 0; i < 4; ++i)
#pragma unroll
        for (int jj = 0; jj < 4; ++jj) acc[i][jj] = zero;

    for (int k0 = 0; k0 < KP; k0 += 32) {
#pragma unroll
        for (int s = 0; s < 2; ++s) {
            int slot = tid + s * 256;
            int row = slot >> 2, c16 = slot & 3;
            uint4 v = *reinterpret_cast<const uint4*>(
                &A[(size_t)(m0 + row) * KP + k0 + c16 * 8]);
            *reinterpret_cast<uint4*>(&Alds[row * LDSW + c16 * 8]) = v;
        }
#pragma unroll
        for (int s = 0; s < 2; ++s) {
            int slot = tid + s * 256;
            int row = slot >> 2, c8 = slot & 3;
            int k = k0 + c8 * 8;
            __align__(16) unsigned short tmp[8];
            if (k + 7 < H) {
                const float* src = &W[(size_t)(n0 + row) * H + k];
                float4 f0 = *reinterpret_cast<const float4*>(src);
                float4 f1 = *reinterpret_cast<const float4*>(src + 4);
                tmp[0] = f2bf(f0.x); tmp[1] = f2bf(f0.y);
                tmp[2] = f2bf(f0.z); tmp[3] = f2bf(f0.w);
                tmp[4] = f2bf(f1.x); tmp[5] = f2bf(f1.y);
                tmp[6] = f2bf(f1.z); tmp[7] = f2bf(f1.w);
            } else {
#pragma unroll
                for (int jv = 0; jv < 8; ++jv) {
                    int kk = k + jv;
                    tmp[jv] = (kk < H) ? f2bf(W[(size_t)(n0 + row) * H + kk])
                                       : (unsigned short)0;
                }
            }
            *reinterpret_cast<uint4*>(&Bl[row * LDSW + c8 * 8]) =
                *reinterpret_cast<const uint4*>(tmp);
        }
        __syncthreads();
        bf16x8 af[4], bfm[4];
#pragma unroll
        for (int i = 0; i < 4; ++i) {
            int row = wm * 64 + i * 16 + (lane & 15);
            af[i] = *reinterpret_cast<const bf16x8*>(&Alds[row * LDSW + (lane >> 4) * 8]);
        }
#pragma unroll
        for (int i = 0; i < 4; ++i) {
            int row = wn * 64 + i * 16 + (lane & 15);
            bfm[i] = *reinterpret_cast<const bf16x8*>(&Bl[row * LDSW + (lane >> 4) * 8]);
        }
#pragma unroll
        for (int i = 0; i < 4; ++i)
#pragma unroll
            for (int jj = 0; jj < 4; ++jj)
                acc[i][jj] = __builtin_amdgcn_mfma_f32_16x16x32_bf16(
                    af[i], bfm[jj], acc[i][jj], 0, 0, 0);
        __syncthreads();
    }
#pragma unroll
    for (int jj = 0; jj < 4; ++jj) {
        int col = n0 + wn * 64 + jj * 16 + (lane & 15);
        float bo = bout[col];
#pragma unroll
        for (int i = 0; i < 4; ++i) {
            int rb = m0 + wm * 64 + i * 16 + (lane >> 4) * 4;
            f32x4 v = acc[i][jj];
#pragma unroll
            for (int r = 0; r < 4; ++r)
                out[(size_t)(rb + r) * VV + col] = v[r] + bo;
        }
    }
}

// ---------------- host ----------------
extern "C" void kernel_launch(void* const* d_in, const int* in_sizes, int n_in,
                              void* d_out, int out_size, void* d_ws, size_t ws_size,
                              hipStream_t stream) {
    const int*   x       = (const int*)d_in[0];
    const int*   y       = (const int*)d_in[1];
    const float* h0      = (const float*)d_in[2];
    const float* EN      = (const float*)d_in[3];
    const float* ZH      = (const float*)d_in[4];
    const float* enc_Wih = (const float*)d_in[5];
    const float* enc_Whh = (const float*)d_in[6];
    const float* enc_bih = (const float*)d_in[7];
    const float* enc_bhh = (const float*)d_in[8];
    const float* dec_Wih = (const float*)d_in[9];
    const float* dec_Whh = (const float*)d_in[10];
    const float* dec_bih = (const float*)d_in[11];
    const float* dec_bhh = (const float*)d_in[12];
    const float* W_out   = (const float*)d_in[13];
    const float* b_out   = (const float*)d_in[14];
    float* out = (float*)d_out;
    char* base = (char*)d_ws;

    const size_t needA = 22549120, needB = 2069120;
    bool bigws = (ws_size >= needA);
    if (!bigws && ws_size < needB) return;

    float* WT = (float*)base;
    float *s2_;
    unsigned short *hdec, *Wb = nullptr;
    if (bigws) {
        Wb   = (unsigned short*)(base + 720000);
        s2_  = (float*)(base + 21200000);
        hdec = (unsigned short*)(base + 21238400);
    } else {
        s2_  = (float*)(base + 720000);
        hdec = (unsigned short*)(base + 758400);
    }
    float* P  = out;                 // [4096x300] f32 (d_out scratch, dead before GEMM)
    float* t1 = out + 2000000;       // [2048x304] f32 (disjoint)

    transpose2<<<dim3(10, 10, 2), dim3(32, 8), 0, stream>>>(enc_Wih, dec_Wih, WT);
    pproj<<<(BB * S_SRC) / RPB, 192, 0, stream>>>(x, EN, WT, enc_bih, enc_bhh, P);
    int mega_grid = bigws ? (ENC_BLK + HDEC_BLK + WCVT_BLK) : (ENC_BLK + HDEC_BLK);
    mega<<<mega_grid, MEGA_T, 0, stream>>>(h0, P, enc_Whh, dec_Whh, dec_bhh, s2_,
                                           y, ZH, WT + 90000, dec_bih, t1,
                                           W_out, Wb);
    hdec_fin<<<M_ROWS / 8, 256, 0, stream>>>(t1, s2_, hdec);
    if (bigws) {
        gemm2<<<4000, 256, 0, stream>>>(hdec, Wb, b_out, out);
    } else {
        gemm_out<<<dim3(VV / 128, M_ROWS / 128), 256, 0, stream>>>(hdec, W_out, b_out, out);
    }
}

// Round 11
// 255.389 us; speedup vs baseline: 1.2453x; 1.0216x over previous
//
#include <hip/hip_runtime.h>
#include <hip/hip_bf16.h>
#include <stdint.h>

#define BB 32
#define S_SRC 128
#define S_TGT 64
#define H 300
#define VV 32000
#define M_ROWS (BB * S_TGT)   // 2048
#define KP 320                // K padded to multiple of 64

#define MEGA_T 640
#define ENC_BLK 32
#define HDEC_BLK 128          // 16 rows each
#define WCVT_BLK 96

typedef __attribute__((ext_vector_type(8))) __bf16 bf16x8;
typedef __attribute__((ext_vector_type(4))) float f32x4;
typedef __attribute__((ext_vector_type(4))) unsigned short u16x4;
typedef __attribute__((ext_vector_type(2))) __fp16 f16x2;

#if defined(__has_builtin)
#if __has_builtin(__builtin_amdgcn_fdot2)
#define HAVE_FDOT2 1
#endif
#endif

__device__ inline unsigned short f2bf(float f) {
    union { float f; unsigned u; } v; v.f = f;
    unsigned r = (v.u + 0x7FFF + ((v.u >> 16) & 1)) >> 16;  // RNE
    return (unsigned short)r;
}

__device__ __forceinline__ float ftanh(float x) {
    float e = __builtin_amdgcn_exp2f(x * 2.8853900817779268f);
    return 1.0f - 2.0f * __builtin_amdgcn_rcpf(e + 1.0f);
}

__device__ __forceinline__ float fdot2(f16x2 a, f16x2 b, float c) {
#ifdef HAVE_FDOT2
    return __builtin_amdgcn_fdot2(a, b, c, false);
#else
    return c + (float)a.x * (float)b.x + (float)a.y * (float)b.y;
#endif
}

__device__ __forceinline__ void gl_lds16(const void* g, void* l) {
    __builtin_amdgcn_global_load_lds(
        (const __attribute__((address_space(1))) void*)g,
        (__attribute__((address_space(3))) void*)l, 16, 0, 0);
}

// ---------------- transpose enc_Wih, dec_Wih -> ws ----------------
__global__ void transpose2(const float* W0, const float* W1, float* dst) {
    const float* srcs[2] = {W0, W1};
    const float* src = srcs[blockIdx.z];
    float* d = dst + (size_t)blockIdx.z * (H * H);
    __shared__ float tile[32][33];
    int j0 = blockIdx.y * 32, k0 = blockIdx.x * 32;
    for (int r = threadIdx.y; r < 32; r += blockDim.y) {
        int j = j0 + r, k = k0 + threadIdx.x;
        tile[r][threadIdx.x] = (j < H && k < H) ? src[(size_t)j * H + k] : 0.f;
    }
    __syncthreads();
    for (int r = threadIdx.y; r < 32; r += blockDim.y) {
        int k = k0 + r, j = j0 + threadIdx.x;
        if (k < H && j < H) d[(size_t)k * H + j] = tile[threadIdx.x][r];
    }
}

// ---------------- P[m][j] = EN[x[m]] @ WihT + bih + bhh  (m = b*128+t) --------
#define RPB 8
__global__ __launch_bounds__(192) void pproj(const int* __restrict__ x,
                                             const float* __restrict__ EN,
                                             const float* __restrict__ WihT,
                                             const float* __restrict__ bih,
                                             const float* __restrict__ bhh,
                                             float* __restrict__ P) {
    __shared__ float xe[RPB][H];
    int m0 = blockIdx.x * RPB;
    int tid = threadIdx.x;
    for (int r = 0; r < RPB; ++r) {
        int idx = x[m0 + r];
        for (int c = tid; c < H; c += 192) xe[r][c] = EN[(size_t)idx * H + c];
    }
    __syncthreads();
    if (tid < 150) {
        int j = tid * 2;
        float a0[RPB], a1[RPB];
#pragma unroll
        for (int r = 0; r < RPB; ++r) { a0[r] = 0.f; a1[r] = 0.f; }
        const float* wp = WihT + j;
        for (int k = 0; k < H; ++k) {
            float2 w = *reinterpret_cast<const float2*>(wp + (size_t)k * H);
#pragma unroll
            for (int r = 0; r < RPB; ++r) {
                float xv = xe[r][k];
                a0[r] += xv * w.x; a1[r] += xv * w.y;
            }
        }
        float b0 = bih[j] + bhh[j], b1 = bih[j + 1] + bhh[j + 1];
#pragma unroll
        for (int r = 0; r < RPB; ++r) {
            P[(size_t)(m0 + r) * H + j]     = a0[r] + b0;
            P[(size_t)(m0 + r) * H + j + 1] = a1[r] + b1;
        }
    }
}

// ---------------- MEGA kernel: 3 concurrent roles by blockIdx ----------------
__global__ __launch_bounds__(MEGA_T) void mega(
    const float* __restrict__ h0, const float* __restrict__ P,
    const float* __restrict__ Whh,
    const float* __restrict__ dWhh, const float* __restrict__ dbhh,
    float* __restrict__ s2,
    const int* __restrict__ yv, const float* __restrict__ ZH,
    const float* __restrict__ WihT_d, const float* __restrict__ bih_d,
    float* __restrict__ t1,
    const float* __restrict__ W, unsigned short* __restrict__ Wb) {
    __shared__ union {
        __fp16 hb[2][304];      // encoder h double-buffer (f16)
        float  ye[16][304];     // hdec embedding tile
    } L;
    int blk = blockIdx.x, tid = threadIdx.x;

    if (blk < ENC_BLK) {
        // ================= encoder =================
        int b = blk;
        bool act = tid < 600;
        int j = tid >> 1, half = tid & 1;   // row j, k-half
        f16x2 w[76];
        if (act) {
            const float* wr = Whh + (size_t)j * H + half * 150;
#pragma unroll
            for (int i = 0; i < 75; ++i) {
                float2 f = *reinterpret_cast<const float2*>(wr + 2 * i);
                w[i] = __builtin_amdgcn_cvt_pkrtz(f.x, f.y);
            }
            w[75] = __builtin_amdgcn_cvt_pkrtz(0.f, 0.f);
        }
        if (act && half == 0) {
            int pos = j < 150 ? j : j + 2;
            L.hb[0][pos] = (__fp16)h0[(size_t)b * H + j];
        }
        if (tid >= 600 && tid < 608) {
            int pi = tid - 600, bufi = pi >> 2, q = pi & 3;
            int idx = (q < 2) ? (150 + q) : (302 + (q - 2));
            L.hb[bufi][idx] = (__fp16)0.f;
        }
        __syncthreads();

        const float* Pb = P + (size_t)b * S_SRC * H;
        int cur = 0;
        for (int t = 0; t < S_SRC; ++t) {
            float pv = 0.f;
            if (act && half == 0) pv = Pb[(size_t)t * H + j];   // hides under dots
            if (act) {
                float a0 = 0.f, a1 = 0.f, a2 = 0.f, a3 = 0.f;
                const uint2* hp =
                    reinterpret_cast<const uint2*>(&L.hb[cur][half * 152]);
#pragma unroll
                for (int i = 0; i < 38; i += 2) {
                    uint2 qa = hp[i];
                    uint2 qb = hp[i + 1];
                    a0 = fdot2(w[2 * i],     __builtin_bit_cast(f16x2, qa.x), a0);
                    a1 = fdot2(w[2 * i + 1], __builtin_bit_cast(f16x2, qa.y), a1);
                    a2 = fdot2(w[2 * i + 2], __builtin_bit_cast(f16x2, qb.x), a2);
                    a3 = fdot2(w[2 * i + 3], __builtin_bit_cast(f16x2, qb.y), a3);
                }
                float a = (a0 + a1) + (a2 + a3);
                float tot = a + __shfl_xor(a, 1, 64);   // pair (2j,2j+1) same wave
                if (half == 0) {
                    float hv = ftanh(tot + pv);
                    int pos = j < 150 ? j : j + 2;
                    L.hb[cur ^ 1][pos] = (__fp16)hv;
                }
            }
            __syncthreads();
            cur ^= 1;
        }
        // ===== fused s2 tail: s2[b] = h @ dWhh^T + dbhh =====
        if (act) {
            const float* wr = dWhh + (size_t)j * H + half * 150;
            const uint2* hp = reinterpret_cast<const uint2*>(&L.hb[cur][half * 152]);
            float a0 = 0.f, a1 = 0.f;
#pragma unroll
            for (int i = 0; i < 37; ++i) {
                uint2 q = hp[i];
                f16x2 hA = __builtin_bit_cast(f16x2, q.x);
                f16x2 hB = __builtin_bit_cast(f16x2, q.y);
                float4 wf = *reinterpret_cast<const float4*>(wr + 4 * i);
                a0 += wf.x * (float)hA.x + wf.y * (float)hA.y;
                a1 += wf.z * (float)hB.x + wf.w * (float)hB.y;
            }
            {
                f16x2 hA = __builtin_bit_cast(f16x2,
                    reinterpret_cast<const uint*>(&L.hb[cur][half * 152])[74]);
                float2 wf = *reinterpret_cast<const float2*>(wr + 148);
                a0 += wf.x * (float)hA.x + wf.y * (float)hA.y;
            }
            float a = a0 + a1;
            float tot = a + __shfl_xor(a, 1, 64);
            if (half == 0) s2[(size_t)b * H + j] = tot + dbhh[j];
        }
    } else if (blk < ENC_BLK + HDEC_BLK) {
        // ================= hdec partial GEMM =================
        int bi = blk - ENC_BLK;
        int m0 = bi * 16;
        for (int i = tid; i < 16 * 304; i += MEGA_T) {
            int r = i / 304, cc = i - r * 304;
            L.ye[r][cc] = (cc < H) ? ZH[(size_t)yv[m0 + r] * H + cc] : 0.f;
        }
        __syncthreads();
        if (tid < 600) {
            int rg = tid / 150, jp = tid - rg * 150, j0 = 2 * jp;
            float a[4][2] = {};
            const float* wp = WihT_d + j0;
            for (int k = 0; k < H; k += 2) {
                float2 wa = *reinterpret_cast<const float2*>(wp + (size_t)k * H);
                float2 wb = *reinterpret_cast<const float2*>(wp + (size_t)(k + 1) * H);
#pragma unroll
                for (int r = 0; r < 4; ++r) {
                    float2 x = *reinterpret_cast<const float2*>(&L.ye[rg * 4 + r][k]);
                    a[r][0] += x.x * wa.x + x.y * wb.x;
                    a[r][1] += x.x * wa.y + x.y * wb.y;
                }
            }
            float b0 = bih_d[j0], b1 = bih_d[j0 + 1];
#pragma unroll
            for (int r = 0; r < 4; ++r) {
                *reinterpret_cast<float2*>(&t1[(size_t)(m0 + rg * 4 + r) * 304 + j0]) =
                    make_float2(a[r][0] + b0, a[r][1] + b1);
            }
        }
    } else if (Wb != nullptr) {
        // ================= wcvt =================
        for (int id = (blk - (ENC_BLK + HDEC_BLK)) * MEGA_T + tid; id < VV * 80;
             id += WCVT_BLK * MEGA_T) {
            int row = id / 80, cq = id - row * 80;
            int k = cq * 4;
            u16x4 o;
            if (k < H) {
                float4 f = *reinterpret_cast<const float4*>(W + (size_t)row * H + k);
                o[0] = f2bf(f.x); o[1] = f2bf(f.y); o[2] = f2bf(f.z); o[3] = f2bf(f.w);
            } else {
                o[0] = 0; o[1] = 0; o[2] = 0; o[3] = 0;
            }
            *reinterpret_cast<u16x4*>(Wb + (size_t)row * KP + k) = o;
        }
    }
}

// ---------------- hdec[m][j] = bf16(tanh(t1[m][j] + s2[b][j])), pad to 320 ---
__global__ __launch_bounds__(128) void hdec_fin(const float* __restrict__ t1,
                                                const float* __restrict__ s2,
                                                unsigned short* __restrict__ hdec) {
    int blk = blockIdx.x, tid = threadIdx.x;   // 512 blocks x 4 rows
    for (int i = tid; i < 4 * KP; i += 128) {
        int r = i / KP, j = i - r * KP;
        int m = blk * 4 + r, b = m >> 6;
        unsigned short v = 0;
        if (j < H)
            v = f2bf(ftanh(t1[(size_t)m * 304 + j] + s2[(size_t)b * H + j]));
        hdec[(size_t)m * KP + j] = v;
    }
}

// ---------------- out = hdec[2048,320] @ Wb[32000,320]^T + b_out -------------
// PROVEN BEST: 128x128 tile, BK=64, dbuf LDS, gl_lds w16, prefetch-after-
// barrier (32 MFMAs cover), both-sides XOR swizzle, XCD-bijective m-fastest.
// NEW: setprio around the MFMA cluster — 2 independent blocks/CU give wave
// phase-diversity (one staging/storing while the other MFMAs), so priority
// lets MFMA-phase waves win issue arbitration (T5 regime).
__global__ __launch_bounds__(256) void gemm2(const unsigned short* __restrict__ A,
                                             const unsigned short* __restrict__ Wb,
                                             const float* __restrict__ bout,
                                             float* __restrict__ out) {
    __shared__ unsigned short Al[2][128 * 64];
    __shared__ unsigned short Blds[2][128 * 64];
    int tid = threadIdx.x;
    int lane = tid & 63, wv = tid >> 6;
    int wm = wv >> 1, wn = wv & 1;           // 2x2 waves, 64x64 each

    int orig = blockIdx.x;                    // 4000 blocks
    int wg = (orig & 7) * 500 + (orig >> 3);  // bijective XCD swizzle (4000%8==0)
    int mi = wg & 15, ni = wg >> 4;           // m-fastest
    int m0 = mi * 128, n0 = ni * 128;

    int rowb = tid >> 3;
    int sc2 = (tid & 7) ^ (rowb & 7);         // pre-swizzled source chunk

    f32x4 acc[4][4];
    f32x4 zero = {0.f, 0.f, 0.f, 0.f};
#pragma unroll
    for (int i = 0; i < 4; ++i)
#pragma unroll
        for (int j = 0; j < 4; ++j) acc[i][j] = zero;

    // prologue stage k-tile 0 into buf 0
#pragma unroll
    for (int i = 0; i < 4; ++i) {
        int row = i * 32 + rowb;
        gl_lds16(A + (size_t)(m0 + row) * KP + sc2 * 8, &Al[0][(i * 256 + tid) * 8]);
    }
#pragma unroll
    for (int i = 0; i < 4; ++i) {
        int row = i * 32 + rowb;
        gl_lds16(Wb + (size_t)(n0 + row) * KP + sc2 * 8, &Blds[0][(i * 256 + tid) * 8]);
    }

    for (int t = 0; t < 5; ++t) {
        __syncthreads();   // drains vmcnt: stage(t) visible; prev reads done
        int buf = t & 1;
        if (t < 4) {       // prefetch first: max latency cover before next barrier
            int k0 = (t + 1) * 64, nb = buf ^ 1;
#pragma unroll
            for (int i = 0; i < 4; ++i) {
                int row = i * 32 + rowb;
                gl_lds16(A + (size_t)(m0 + row) * KP + k0 + sc2 * 8,
                         &Al[nb][(i * 256 + tid) * 8]);
            }
#pragma unroll
            for (int i = 0; i < 4; ++i) {
                int row = i * 32 + rowb;
                gl_lds16(Wb + (size_t)(n0 + row) * KP + k0 + sc2 * 8,
                         &Blds[nb][(i * 256 + tid) * 8]);
            }
        }
        bf16x8 af[2][4], bb[2][4];
#pragma unroll
        for (int ks = 0; ks < 2; ++ks)
#pragma unroll
            for (int i = 0; i < 4; ++i) {
                int ch = (ks * 4 + (lane >> 4)) ^ (lane & 7);  // read-side XOR
                int rowA = wm * 64 + i * 16 + (lane & 15);
                af[ks][i] = *reinterpret_cast<const bf16x8*>(&Al[buf][rowA * 64 + ch * 8]);
                int rowB = wn * 64 + i * 16 + (lane & 15);
                bb[ks][i] = *reinterpret_cast<const bf16x8*>(&Blds[buf][rowB * 64 + ch * 8]);
            }
        __builtin_amdgcn_s_setprio(1);
#pragma unroll
        for (int ks = 0; ks < 2; ++ks)
#pragma unroll
            for (int i = 0; i < 4; ++i)
#pragma unroll
                for (int j = 0; j < 4; ++j)
                    acc[i][j] = __builtin_amdgcn_mfma_f32_16x16x32_bf16(
                        af[ks][i], bb[ks][j], acc[i][j], 0, 0, 0);
        __builtin_amdgcn_s_setprio(0);
    }

    // epilogue: D row=(lane>>4)*4+r, col=lane&15
#pragma unroll
    for (int j = 0; j < 4; ++j) {
        int col = n0 + wn * 64 + j * 16 + (lane & 15);
        float bo = bout[col];
#pragma unroll
        for (int i = 0; i < 4; ++i) {
            int rb = m0 + wm * 64 + i * 16 + (lane >> 4) * 4;
            f32x4 v = acc[i][j];
#pragma unroll
            for (int r = 0; r < 4; ++r)
                out[(size_t)(rb + r) * VV + col] = v[r] + bo;
        }
    }
}

// ---------------- fallback GEMM (reads W f32) for small ws -------------------
#define LDSW 40
__global__ __launch_bounds__(256) void gemm_out(const unsigned short* __restrict__ A,
                                                const float* __restrict__ W,
                                                const float* __restrict__ bout,
                                                float* __restrict__ out) {
    __shared__ __align__(16) unsigned short Alds[128 * LDSW];
    __shared__ __align__(16) unsigned short Bl[128 * LDSW];
    int tid = threadIdx.x;
    int lane = tid & 63, wv = tid >> 6;
    int wm = wv >> 1, wn = wv & 1;
    int m0 = blockIdx.y * 128, n0 = blockIdx.x * 128;

    f32x4 acc[4][4];
    f32x4 zero = {0.f, 0.f, 0.f, 0.f};
#pragma unroll
    for (int i = 0; i < 4; ++i)
#pragma unroll
        for (int jj = 0; jj < 4; ++jj) acc[i][jj] = zero;

    for (int k0 = 0; k0 < KP; k0 += 32) {
#pragma unroll
        for (int s = 0; s < 2; ++s) {
            int slot = tid + s * 256;
            int row = slot >> 2, c16 = slot & 3;
            uint4 v = *reinterpret_cast<const uint4*>(
                &A[(size_t)(m0 + row) * KP + k0 + c16 * 8]);
            *reinterpret_cast<uint4*>(&Alds[row * LDSW + c16 * 8]) = v;
        }
#pragma unroll
        for (int s = 0; s < 2; ++s) {
            int slot = tid + s * 256;
            int row = slot >> 2, c8 = slot & 3;
            int k = k0 + c8 * 8;
            __align__(16) unsigned short tmp[8];
            if (k + 7 < H) {
                const float* src = &W[(size_t)(n0 + row) * H + k];
                float4 f0 = *reinterpret_cast<const float4*>(src);
                float4 f1 = *reinterpret_cast<const float4*>(src + 4);
                tmp[0] = f2bf(f0.x); tmp[1] = f2bf(f0.y);
                tmp[2] = f2bf(f0.z); tmp[3] = f2bf(f0.w);
                tmp[4] = f2bf(f1.x); tmp[5] = f2bf(f1.y);
                tmp[6] = f2bf(f1.z); tmp[7] = f2bf(f1.w);
            } else {
#pragma unroll
                for (int jv = 0; jv < 8; ++jv) {
                    int kk = k + jv;
                    tmp[jv] = (kk < H) ? f2bf(W[(size_t)(n0 + row) * H + kk])
                                       : (unsigned short)0;
                }
            }
            *reinterpret_cast<uint4*>(&Bl[row * LDSW + c8 * 8]) =
                *reinterpret_cast<const uint4*>(tmp);
        }
        __syncthreads();
        bf16x8 af[4], bfm[4];
#pragma unroll
        for (int i = 0; i < 4; ++i) {
            int row = wm * 64 + i * 16 + (lane & 15);
            af[i] = *reinterpret_cast<const bf16x8*>(&Alds[row * LDSW + (lane >> 4) * 8]);
        }
#pragma unroll
        for (int i = 0; i < 4; ++i) {
            int row = wn * 64 + i * 16 + (lane & 15);
            bfm[i] = *reinterpret_cast<const bf16x8*>(&Bl[row * LDSW + (lane >> 4) * 8]);
        }
#pragma unroll
        for (int i = 0; i < 4; ++i)
#pragma unroll
            for (int jj = 0; jj < 4; ++jj)
                acc[i][jj] = __builtin_amdgcn_mfma_f32_16x16x32_bf16(
                    af[i], bfm[jj], acc[i][jj], 0, 0, 0);
        __syncthreads();
    }
#pragma unroll
    for (int jj = 0; jj < 4; ++jj) {
        int col = n0 + wn * 64 + jj * 16 + (lane & 15);
        float bo = bout[col];
#pragma unroll
        for (int i = 0; i < 4; ++i) {
            int rb = m0 + wm * 64 + i * 16 + (lane >> 4) * 4;
            f32x4 v = acc[i][jj];
#pragma unroll
            for (int r = 0; r < 4; ++r)
                out[(size_t)(rb + r) * VV + col] = v[r] + bo;
        }
    }
}

// ---------------- host ----------------
extern "C" void kernel_launch(void* const* d_in, const int* in_sizes, int n_in,
                              void* d_out, int out_size, void* d_ws, size_t ws_size,
                              hipStream_t stream) {
    const int*   x       = (const int*)d_in[0];
    const int*   y       = (const int*)d_in[1];
    const float* h0      = (const float*)d_in[2];
    const float* EN      = (const float*)d_in[3];
    const float* ZH      = (const float*)d_in[4];
    const float* enc_Wih = (const float*)d_in[5];
    const float* enc_Whh = (const float*)d_in[6];
    const float* enc_bih = (const float*)d_in[7];
    const float* enc_bhh = (const float*)d_in[8];
    const float* dec_Wih = (const float*)d_in[9];
    const float* dec_Whh = (const float*)d_in[10];
    const float* dec_bih = (const float*)d_in[11];
    const float* dec_bhh = (const float*)d_in[12];
    const float* W_out   = (const float*)d_in[13];
    const float* b_out   = (const float*)d_in[14];
    float* out = (float*)d_out;
    char* base = (char*)d_ws;

    const size_t needA = 22549120, needB = 2069120;
    bool bigws = (ws_size >= needA);
    if (!bigws && ws_size < needB) return;

    float* WT = (float*)base;
    float *s2_;
    unsigned short *hdec, *Wb = nullptr;
    if (bigws) {
        Wb   = (unsigned short*)(base + 720000);
        s2_  = (float*)(base + 21200000);
        hdec = (unsigned short*)(base + 21238400);
    } else {
        s2_  = (float*)(base + 720000);
        hdec = (unsigned short*)(base + 758400);
    }
    float* P  = out;                 // [4096x300] f32 (d_out scratch, dead before GEMM)
    float* t1 = out + 2000000;       // [2048x304] f32 (disjoint)

    transpose2<<<dim3(10, 10, 2), dim3(32, 8), 0, stream>>>(enc_Wih, dec_Wih, WT);
    pproj<<<(BB * S_SRC) / RPB, 192, 0, stream>>>(x, EN, WT, enc_bih, enc_bhh, P);
    int mega_grid = bigws ? (ENC_BLK + HDEC_BLK + WCVT_BLK) : (ENC_BLK + HDEC_BLK);
    mega<<<mega_grid, MEGA_T, 0, stream>>>(h0, P, enc_Whh, dec_Whh, dec_bhh, s2_,
                                           y, ZH, WT + 90000, dec_bih, t1,
                                           W_out, Wb);
    hdec_fin<<<M_ROWS / 4, 128, 0, stream>>>(t1, s2_, hdec);
    if (bigws) {
        gemm2<<<4000, 256, 0, stream>>>(hdec, Wb, b_out, out);
    } else {
        gemm_out<<<dim3(VV / 128, M_ROWS / 128), 256, 0, stream>>>(hdec, W_out, b_out, out);
    }
}